// Round 1
// baseline (145.168 us; speedup 1.0000x reference)
//
#include <hip/hip_runtime.h>
#include <hip/hip_bf16.h>
#include <cmath>

// Problem constants (from reference): V=100000, E=128, B=32, S=1024, N=16
#define NS_ROWS   (32 * 1024)   // B*S
#define NS_E      128
#define NS_NEG    16
#define NS_TARGETS (NS_NEG + 1)

__device__ __forceinline__ float log_sigmoid_f(float x) {
    // log_sigmoid(x) = min(x,0) - log1p(exp(-|x|))   (numerically stable)
    return fminf(x, 0.0f) - log1pf(__expf(-fabsf(x)));
}

__global__ __launch_bounds__(256) void neg_sampling_kernel(
    const int*   __restrict__ sentence,   // [ROWS]
    const float* __restrict__ context,    // [ROWS, 128]
    const int*   __restrict__ neg,        // [ROWS, 16]
    const float* __restrict__ W,          // [V, 128]
    float*       __restrict__ out)        // scalar
{
    const int wave = threadIdx.x >> 6;          // 4 waves per block
    const int lane = threadIdx.x & 63;
    const int row  = (blockIdx.x << 2) + wave;  // one (b,s) row per wave

    // context row: 64 lanes x float2 = 128 floats, coalesced 512B
    const float2 c = reinterpret_cast<const float2*>(context)[row * 64 + lane];

    // Load all 17 indices (wave-uniform addresses -> HW broadcast)
    int idx[NS_TARGETS];
    idx[0] = sentence[row];
#pragma unroll
    for (int n = 0; n < NS_NEG; ++n) idx[n + 1] = neg[row * NS_NEG + n];

    // Issue all 17 gathered W-row loads; FMA into per-target partials.
    float score[NS_TARGETS];
#pragma unroll
    for (int t = 0; t < NS_TARGETS; ++t) {
        const float2 wv = reinterpret_cast<const float2*>(W)[idx[t] * 64 + lane];
        score[t] = c.x * wv.x + c.y * wv.y;
    }

    // Butterfly-reduce each score across the 64-lane wave.
#pragma unroll
    for (int t = 0; t < NS_TARGETS; ++t) {
        float v = score[t];
#pragma unroll
        for (int m = 32; m >= 1; m >>= 1) v += __shfl_xor(v, m, 64);
        score[t] = v;
    }

    // loss for this row
    float loss = log_sigmoid_f(score[0]);
#pragma unroll
    for (int n = 1; n < NS_TARGETS; ++n) loss += log_sigmoid_f(-score[n]);

    // Block reduce (4 waves) -> one atomic per block.
    __shared__ float smem[4];
    if (lane == 0) smem[wave] = loss;
    __syncthreads();
    if (threadIdx.x == 0) {
        const float t = smem[0] + smem[1] + smem[2] + smem[3];
        atomicAdd(out, -t);
    }
}

extern "C" void kernel_launch(void* const* d_in, const int* in_sizes, int n_in,
                              void* d_out, int out_size, void* d_ws, size_t ws_size,
                              hipStream_t stream) {
    const int*   sentence = (const int*)d_in[0];
    const float* context  = (const float*)d_in[1];
    const int*   neg      = (const int*)d_in[2];
    const float* W        = (const float*)d_in[3];
    float*       out      = (float*)d_out;

    // d_out is poisoned and not re-poisoned between replays: zero it each call.
    hipMemsetAsync(out, 0, sizeof(float), stream);

    const int blocks = NS_ROWS / 4;  // 4 rows (waves) per 256-thread block
    neg_sampling_kernel<<<blocks, 256, 0, stream>>>(sentence, context, neg, W, out);
}

// Round 2
// 59.226 us; speedup vs baseline: 2.4511x; 2.4511x over previous
//
#include <hip/hip_runtime.h>
#include <hip/hip_bf16.h>
#include <cmath>

// Problem constants: V=100000, E=128, B=32, S=1024, N=16
#define NS_ROWS    32768          // B*S
#define NS_NEG     16
#define NS_TARGETS 17             // 1 pos + 16 neg
#define NS_TILE    15             // rows per 256-thread block (15*17 = 255)
#define NS_CPAD    132            // padded context row stride in floats (528 B)

__device__ __forceinline__ float log_sigmoid_f(float x) {
    // log_sigmoid(x) = min(x,0) - log1p(exp(-|x|))   (numerically stable)
    return fminf(x, 0.0f) - log1pf(__expf(-fabsf(x)));
}

__global__ __launch_bounds__(256) void neg_sampling_kernel(
    const int*   __restrict__ sentence,   // [ROWS]
    const float* __restrict__ context,    // [ROWS, 128]
    const int*   __restrict__ neg,        // [ROWS, 16]
    const float* __restrict__ W,          // [V, 128]
    float*       __restrict__ out)        // scalar
{
    __shared__ float cctx[NS_TILE][NS_CPAD];   // 15 x 132 floats = 7.9 KB

    const int tid     = threadIdx.x;
    const int rowbase = blockIdx.x * NS_TILE;

    // --- Stage 15 context rows into LDS, coalesced float4 (480 float4) ---
    for (int i = tid; i < NS_TILE * 32; i += 256) {
        const int r  = i >> 5;          // local row
        const int e4 = i & 31;          // float4 index within row
        const int grow = rowbase + r;
        if (grow < NS_ROWS) {
            const float4 v = reinterpret_cast<const float4*>(context)[grow * 32 + e4];
            *reinterpret_cast<float4*>(&cctx[r][e4 * 4]) = v;
        }
    }
    __syncthreads();

    // --- One thread per (row, target): lane-local 128-dot, no shuffles ---
    float loss = 0.0f;
    if (tid < NS_TILE * NS_TARGETS) {                 // 255 active threads
        const int lrow = (tid * 241) >> 12;           // tid / 17 (exact for tid<255)
        const int tgt  = tid - lrow * NS_TARGETS;     // tid % 17
        const int row  = rowbase + lrow;
        if (row < NS_ROWS) {
            const int idx = (tgt == 0) ? sentence[row]
                                       : neg[row * NS_NEG + (tgt - 1)];
            const float4* __restrict__ wr =
                reinterpret_cast<const float4*>(W) + (long)idx * 32;
            const float4* __restrict__ cr =
                reinterpret_cast<const float4*>(&cctx[lrow][0]);

            float acc = 0.0f;
#pragma unroll 8
            for (int e = 0; e < 32; ++e) {
                const float4 w = wr[e];
                const float4 c = cr[e];
                acc += w.x * c.x + w.y * c.y + w.z * c.z + w.w * c.w;
            }
            const float x = (tgt == 0) ? acc : -acc;
            loss = log_sigmoid_f(x);
        }
    }

    // --- One butterfly per wave + block reduce + one atomic per block ---
#pragma unroll
    for (int m = 32; m >= 1; m >>= 1) loss += __shfl_xor(loss, m, 64);

    __shared__ float smem[4];
    const int wave = tid >> 6, lane = tid & 63;
    if (lane == 0) smem[wave] = loss;
    __syncthreads();
    if (tid == 0) {
        atomicAdd(out, -(smem[0] + smem[1] + smem[2] + smem[3]));
    }
}

extern "C" void kernel_launch(void* const* d_in, const int* in_sizes, int n_in,
                              void* d_out, int out_size, void* d_ws, size_t ws_size,
                              hipStream_t stream) {
    const int*   sentence = (const int*)d_in[0];
    const float* context  = (const float*)d_in[1];
    const int*   neg      = (const int*)d_in[2];
    const float* W        = (const float*)d_in[3];
    float*       out      = (float*)d_out;

    // d_out is poisoned and not re-poisoned between replays: zero it each call.
    hipMemsetAsync(out, 0, sizeof(float), stream);

    const int blocks = (NS_ROWS + NS_TILE - 1) / NS_TILE;  // 2185
    neg_sampling_kernel<<<blocks, 256, 0, stream>>>(sentence, context, neg, W, out);
}

// Round 3
// 51.889 us; speedup vs baseline: 2.7977x; 1.1414x over previous
//
#include <hip/hip_runtime.h>
#include <hip/hip_bf16.h>
#include <cmath>

// Problem constants: V=100000, E=128, B=32, S=1024, N=16
#define NS_ROWS    32768          // B*S
#define NS_NEG     16
#define NS_TARGETS 17             // 1 pos + 16 neg
#define NS_TILE    15             // rows per 1024-thread block (15*17*4 = 1020 lanes)
#define NS_CPAD    132            // padded context row stride in floats (528 B, 16B-aligned)

__device__ __forceinline__ float log_sigmoid_f(float x) {
    return fminf(x, 0.0f) - log1pf(__expf(-fabsf(x)));
}

__global__ __launch_bounds__(1024) void neg_sampling_kernel(
    const int*   __restrict__ sentence,   // [ROWS]
    const float* __restrict__ context,    // [ROWS, 128]
    const int*   __restrict__ neg,        // [ROWS, 16]
    const float* __restrict__ W,          // [V, 128]
    float*       __restrict__ out)        // scalar
{
    __shared__ float cctx[NS_TILE][NS_CPAD];   // 7.9 KB
    __shared__ float wsum[16];

    const int tid     = threadIdx.x;
    const int rowbase = blockIdx.x * NS_TILE;

    // --- Quad assignment: 4 lanes per (row, target) ---
    const int group = tid >> 2;               // 0..255
    const int sub   = tid & 3;
    const int lrow  = group / NS_TARGETS;     // 0..15 (group 255 -> 15, guarded below)
    const int tgt   = group - lrow * NS_TARGETS;
    const int row   = rowbase + lrow;
    const bool active = (lrow < NS_TILE) && (row < NS_ROWS);

    // --- Issue gather loads EARLY (before staging sync) so latency overlaps ---
    float4 w0, w1, w2, w3, w4, w5, w6, w7;
    if (active) {
        const int idx = (tgt == 0) ? sentence[row] : neg[row * NS_NEG + (tgt - 1)];
        const float4* __restrict__ wr =
            reinterpret_cast<const float4*>(W) + (size_t)idx * 32 + sub;
        // lanes sub=0..3 read e4 = sub + 4k -> each step = one 64B line per quad
        w0 = wr[0];  w1 = wr[4];  w2 = wr[8];  w3 = wr[12];
        w4 = wr[16]; w5 = wr[20]; w6 = wr[24]; w7 = wr[28];
    } else {
        w0=w1=w2=w3=w4=w5=w6=w7 = make_float4(0.f,0.f,0.f,0.f);
    }

    // --- Stage 15 context rows into LDS (480 float4, coalesced) ---
    if (tid < NS_TILE * 32) {
        const int r  = tid >> 5;
        const int e4 = tid & 31;
        const int grow = rowbase + r;
        if (grow < NS_ROWS) {
            const float4 v = reinterpret_cast<const float4*>(context)[grow * 32 + e4];
            *reinterpret_cast<float4*>(&cctx[r][e4 * 4]) = v;
        }
    }
    __syncthreads();

    // --- Lane-local partial dot (32 floats), read context from LDS ---
    float loss = 0.0f;
    if (active) {
        const float* crow = &cctx[lrow][0];
        float acc = 0.0f;
        {
            float4 c;
            c = *reinterpret_cast<const float4*>(crow + (sub +  0) * 4);
            acc += w0.x*c.x + w0.y*c.y + w0.z*c.z + w0.w*c.w;
            c = *reinterpret_cast<const float4*>(crow + (sub +  4) * 4);
            acc += w1.x*c.x + w1.y*c.y + w1.z*c.z + w1.w*c.w;
            c = *reinterpret_cast<const float4*>(crow + (sub +  8) * 4);
            acc += w2.x*c.x + w2.y*c.y + w2.z*c.z + w2.w*c.w;
            c = *reinterpret_cast<const float4*>(crow + (sub + 12) * 4);
            acc += w3.x*c.x + w3.y*c.y + w3.z*c.z + w3.w*c.w;
            c = *reinterpret_cast<const float4*>(crow + (sub + 16) * 4);
            acc += w4.x*c.x + w4.y*c.y + w4.z*c.z + w4.w*c.w;
            c = *reinterpret_cast<const float4*>(crow + (sub + 20) * 4);
            acc += w5.x*c.x + w5.y*c.y + w5.z*c.z + w5.w*c.w;
            c = *reinterpret_cast<const float4*>(crow + (sub + 24) * 4);
            acc += w6.x*c.x + w6.y*c.y + w6.z*c.z + w6.w*c.w;
            c = *reinterpret_cast<const float4*>(crow + (sub + 28) * 4);
            acc += w7.x*c.x + w7.y*c.y + w7.z*c.z + w7.w*c.w;
        }
        // quad butterfly: all 4 lanes end with the full 128-dot
        acc += __shfl_xor(acc, 1, 64);
        acc += __shfl_xor(acc, 2, 64);
        if (sub == 0) {
            loss = log_sigmoid_f((tgt == 0) ? acc : -acc);
        }
    }

    // --- Wave butterfly + block reduce + one atomic per block ---
#pragma unroll
    for (int m = 32; m >= 1; m >>= 1) loss += __shfl_xor(loss, m, 64);

    const int wave = tid >> 6, lane = tid & 63;
    if (lane == 0) wsum[wave] = loss;
    __syncthreads();
    if (tid == 0) {
        float t = 0.0f;
#pragma unroll
        for (int i = 0; i < 16; ++i) t += wsum[i];
        atomicAdd(out, -t);
    }
}

extern "C" void kernel_launch(void* const* d_in, const int* in_sizes, int n_in,
                              void* d_out, int out_size, void* d_ws, size_t ws_size,
                              hipStream_t stream) {
    const int*   sentence = (const int*)d_in[0];
    const float* context  = (const float*)d_in[1];
    const int*   neg      = (const int*)d_in[2];
    const float* W        = (const float*)d_in[3];
    float*       out      = (float*)d_out;

    hipMemsetAsync(out, 0, sizeof(float), stream);

    const int blocks = (NS_ROWS + NS_TILE - 1) / NS_TILE;  // 2185
    neg_sampling_kernel<<<blocks, 1024, 0, stream>>>(sentence, context, neg, W, out);
}